// Round 1
// baseline (443.635 us; speedup 1.0000x reference)
//
#include <hip/hip_runtime.h>
#include <math.h>

// HungarianLoss: B=128 independent linear assignments on (Q=900 x M=100) cost
// matrices, then matched CE + L1 loss. One block (one 64-lane wave) per batch.
// JV algorithm in float64 mirroring the numpy reference op-for-op so the
// assignment matches except in measure-zero ties.

#define NQ 900   // queries (columns of transposed matrix, m)
#define NG 100   // ground-truth boxes (rows of transposed matrix, n)
#define NC 7     // classes
#define KCOLS 15 // ceil(900/64) columns owned per lane

__global__ __launch_bounds__(64) void hungarian_loss_kernel(
    const float* __restrict__ logits,   // (B,900,7)
    const float* __restrict__ pboxes,   // (B,900,7)
    const int*   __restrict__ glabels,  // (B,100)
    const float* __restrict__ gboxes,   // (B,100,7)
    float* __restrict__ out, float inv_batches)
{
  const int b    = blockIdx.x;
  const int lane = threadIdx.x;

  __shared__ float  s_nlp[NQ * NC];            // -log_softmax per query/class
  __shared__ float  s_px[NQ], s_py[NQ], s_pz[NQ];
  __shared__ float  s_gx[NG], s_gy[NG], s_gz[NG];
  __shared__ int    s_glab[NG];
  __shared__ double s_u[NG + 1];               // row potentials (1-based)
  __shared__ short  s_p[NQ + 1];               // p[j] = row matched to col j (1-based), 0 = free
  __shared__ short  s_way[NQ + 1];

  const float* L  = logits + (size_t)b * NQ * NC;
  const float* PB = pboxes + (size_t)b * NQ * 7;
  const float* GB = gboxes + (size_t)b * NG * 7;
  const int*   GL = glabels + (size_t)b * NG;

  // ---- Phase 1: per-query nlp + xyz staging ----
  for (int q = lane; q < NQ; q += 64) {
    float x[NC];
    #pragma unroll
    for (int c = 0; c < NC; c++) x[c] = L[q * NC + c];
    float mx = x[0];
    #pragma unroll
    for (int c = 1; c < NC; c++) mx = fmaxf(mx, x[c]);
    float s = 0.f;
    #pragma unroll
    for (int c = 0; c < NC; c++) s += expf(x[c] - mx);
    float ls = logf(s);
    #pragma unroll
    for (int c = 0; c < NC; c++) s_nlp[q * NC + c] = ls - (x[c] - mx);
    s_px[q] = PB[q * 7 + 0];
    s_py[q] = PB[q * 7 + 1];
    s_pz[q] = PB[q * 7 + 2];
  }
  for (int g = lane; g < NG; g += 64) {
    s_glab[g] = GL[g];
    s_gx[g] = GB[g * 7 + 0];
    s_gy[g] = GB[g * 7 + 1];
    s_gz[g] = GB[g * 7 + 2];
  }
  for (int t = lane; t <= NG; t += 64) s_u[t] = 0.0;
  for (int t = lane; t <= NQ; t += 64) { s_p[t] = 0; s_way[t] = 0; }
  __syncthreads();

  // Lane-owned column state in registers: lane owns j = lane+1 + 64k (1-based).
  double v_r[KCOLS], minv_r[KCOLS];
  float  cpx[KCOLS], cpy[KCOLS], cpz[KCOLS];
  #pragma unroll
  for (int k = 0; k < KCOLS; k++) {
    v_r[k] = 0.0;
    int j = lane + 1 + (k << 6);
    if (j <= NQ) { cpx[k] = s_px[j-1]; cpy[k] = s_py[j-1]; cpz[k] = s_pz[j-1]; }
    else         { cpx[k] = cpy[k] = cpz[k] = 0.f; }
  }

  const double DINF = __builtin_inf();

  // ---- Phase 2: JV shortest augmenting paths ----
  for (int i = 1; i <= NG; i++) {
    unsigned used_r = 0;   // bit k: owned column lane+1+64k is used
    #pragma unroll
    for (int k = 0; k < KCOLS; k++) minv_r[k] = DINF;
    int j0 = 0;
    int guard = 0;
    for (;;) {
      // mark used[j0] (owning lane flips its local bit; j0==0 tracked implicitly)
      if (j0 > 0 && ((j0 - 1) & 63) == lane) used_r |= 1u << ((j0 - 1) >> 6);
      int    i0   = (j0 == 0) ? i : (int)s_p[j0];
      double u_i0 = s_u[i0];
      int    lab  = s_glab[i0 - 1];
      float  gx = s_gx[i0 - 1], gy = s_gy[i0 - 1], gz = s_gz[i0 - 1];

      double bestv = DINF; int bestj = NQ + 1;
      #pragma unroll
      for (int k = 0; k < KCOLS; k++) {
        int j = lane + 1 + (k << 6);
        if (j <= NQ && !((used_r >> k) & 1u)) {
          float costf = s_nlp[(j - 1) * NC + lab]
                      + (fabsf(cpx[k] - gx) + fabsf(cpy[k] - gy) + fabsf(cpz[k] - gz));
          double cur = ((double)costf - u_i0) - v_r[k];
          if (cur < minv_r[k]) { minv_r[k] = cur; s_way[j] = (short)j0; }
          if (minv_r[k] < bestv) { bestv = minv_r[k]; bestj = j; }  // strict < keeps first index
        }
      }
      // cross-lane min with first-index tie-break (matches np.argmin)
      #pragma unroll
      for (int off = 32; off > 0; off >>= 1) {
        double ov = __shfl_down(bestv, off);
        int    oj = __shfl_down(bestj, off);
        if (ov < bestv || (ov == bestv && oj < bestj)) { bestv = ov; bestj = oj; }
      }
      double delta = __shfl(bestv, 0);
      int    j0n   = __shfl(bestj, 0);
      if (j0n > NQ) break;  // safety: should never trigger (m > n)

      // u[p[used]] += delta; v[used] -= delta; minv[free] -= delta
      #pragma unroll
      for (int k = 0; k < KCOLS; k++) {
        int j = lane + 1 + (k << 6);
        if (j <= NQ) {
          if ((used_r >> k) & 1u) {
            v_r[k] -= delta;
            s_u[(int)s_p[j]] += delta;   // distinct rows across used cols: race-free
          } else {
            minv_r[k] -= delta;
          }
        }
      }
      if (lane == 0) s_u[i] += delta;    // used[0] is always set after iter 1
      __syncthreads();                   // make s_u writes visible for next read

      j0 = j0n;
      if (s_p[j0] == 0) break;           // reached a free column
      if (++guard > NQ) break;           // safety net against hang
    }
    // augment along alternating path
    __syncthreads();                     // s_way writes visible
    if (lane == 0) {
      int j = j0;
      while (j != 0) {
        int j1 = (int)s_way[j];
        s_p[j] = (j1 == 0) ? (short)i : s_p[j1];
        j = j1;
      }
    }
    __syncthreads();
  }

  // ---- Phase 3: matched loss ----
  double ce = 0.0, l1 = 0.0;
  #pragma unroll
  for (int k = 0; k < KCOLS; k++) {
    int j = lane + 1 + (k << 6);
    if (j <= NQ) {
      int pi = (int)s_p[j];
      if (pi > 0) {
        int q = j - 1, g = pi - 1;
        ce += (double)s_nlp[q * NC + s_glab[g]];
        float s = 0.f;
        #pragma unroll
        for (int d = 0; d < 7; d++) s += fabsf(PB[q * 7 + d] - GB[g * 7 + d]);
        l1 += (double)s;
      }
    }
  }
  #pragma unroll
  for (int off = 32; off > 0; off >>= 1) {
    ce += __shfl_down(ce, off);
    l1 += __shfl_down(l1, off);
  }
  if (lane == 0) {
    float batch_loss = (float)((ce * (1.0 / NG) + l1 * (1.0 / (NG * 7.0))));
    atomicAdd(out, batch_loss * inv_batches);
  }
}

extern "C" void kernel_launch(void* const* d_in, const int* in_sizes, int n_in,
                              void* d_out, int out_size, void* d_ws, size_t ws_size,
                              hipStream_t stream) {
  const float* logits  = (const float*)d_in[0];
  const float* pboxes  = (const float*)d_in[1];
  const int*   glabels = (const int*)d_in[2];
  const float* gboxes  = (const float*)d_in[3];
  float* out = (float*)d_out;
  const int B = in_sizes[0] / (NQ * NC);   // 128

  hipMemsetAsync(out, 0, sizeof(float), stream);
  hungarian_loss_kernel<<<dim3(B), dim3(64), 0, stream>>>(
      logits, pboxes, glabels, gboxes, out, 1.0f / (float)B);
}

// Round 2
// 150.589 us; speedup vs baseline: 2.9460x; 2.9460x over previous
//
#include <hip/hip_runtime.h>
#include <math.h>

// HungarianLoss on MI355X.
// K1 (rowmin_kernel): massively parallel per-row argmin -> greedy-init duals u[i]
//   and candidate columns j1[i] (LAPJV row reduction), written to d_ws.
// K2 (solve_kernel): one wave per batch. Greedy claim via LDS atomicMin
//   (winner = lowest row), then JV shortest-augmenting-path Dijkstra for the
//   ~6 unmatched rows with DEFERRED potential updates (u/v touched only at row
//   end), f32 arithmetic, DPP min-reduce, register-resident p/way/v with
//   readlane broadcasts. Matched loss (CE + L1) reduced per wave, atomicAdd.

#define NQ  900    // queries (columns)
#define NQP 960    // padded to 15*64
#define NG  100    // gt boxes (rows)
#define NC  7
#define KS  15     // column slots per lane
#define INFF __builtin_inff()

// ---------- helpers ----------
__device__ __forceinline__ float readlane_f(float x, int l) {
  return __int_as_float(__builtin_amdgcn_readlane(__float_as_int(x), l));
}

template<int CTRL>
__device__ __forceinline__ float dpp_min_step(float x) {
  int y = __builtin_amdgcn_update_dpp(__float_as_int(x), __float_as_int(x),
                                      CTRL, 0xf, 0xf, false);  // old=x -> identity
  return fminf(x, __int_as_float(y));
}
// full-wave min, broadcast to all lanes via readlane(63)
__device__ __forceinline__ float wave_min_b(float x) {
  x = dpp_min_step<0x111>(x);  // row_shr:1
  x = dpp_min_step<0x112>(x);  // row_shr:2
  x = dpp_min_step<0x114>(x);  // row_shr:4
  x = dpp_min_step<0x118>(x);  // row_shr:8
  x = dpp_min_step<0x142>(x);  // row_bcast:15
  x = dpp_min_step<0x143>(x);  // row_bcast:31
  return __int_as_float(__builtin_amdgcn_readlane(__float_as_int(x), 63));
}

template<int CTRL>
__device__ __forceinline__ float dpp_add_step(float x) {
  int y = __builtin_amdgcn_update_dpp(0, __float_as_int(x),
                                      CTRL, 0xf, 0xf, true);   // bound_ctrl -> 0
  return x + __int_as_float(y);
}
__device__ __forceinline__ float wave_sum_b(float x) {
  x = dpp_add_step<0x111>(x);
  x = dpp_add_step<0x112>(x);
  x = dpp_add_step<0x114>(x);
  x = dpp_add_step<0x118>(x);
  x = dpp_add_step<0x142>(x);
  x = dpp_add_step<0x143>(x);
  return __int_as_float(__builtin_amdgcn_readlane(__float_as_int(x), 63));
}

// -log_softmax for one query; identical code in both kernels -> identical bits
__device__ __forceinline__ void nlp7(const float* __restrict__ xq, float* o) {
  float xv[NC];
  #pragma unroll
  for (int c = 0; c < NC; c++) xv[c] = xq[c];
  float mx = xv[0];
  #pragma unroll
  for (int c = 1; c < NC; c++) mx = fmaxf(mx, xv[c]);
  float t[NC]; float se = 0.f;
  #pragma unroll
  for (int c = 0; c < NC; c++) { t[c] = xv[c] - mx; se += __expf(t[c]); }
  float lg = __logf(se);
  #pragma unroll
  for (int c = 0; c < NC; c++) o[c] = lg - t[c];
}

// ---------- K1: per-row argmin over 900 columns ----------
// grid = B*4 blocks of 256 threads; block rb handles rows [rb*25, rb*25+25)
__global__ __launch_bounds__(256) void rowmin_kernel(
    const float* __restrict__ logits, const float* __restrict__ pboxes,
    const int* __restrict__ glabels, const float* __restrict__ gboxes,
    float* __restrict__ wsm, int* __restrict__ wsj)
{
  const int b  = blockIdx.x >> 2;
  const int rb = blockIdx.x & 3;
  const int tid = threadIdx.x, lane = tid & 63, w = tid >> 6;

  __shared__ float s_nlp[NQP * NC];
  __shared__ float s_pb[NQP * 3];

  const float* L  = logits + (size_t)b * NQ * NC;
  const float* PB = pboxes + (size_t)b * NQ * 7;
  const float* GB = gboxes + (size_t)b * NG * 7;
  const int*   GL = glabels + (size_t)b * NG;

  for (int q = tid; q < NQP; q += 256) {
    if (q < NQ) {
      nlp7(&L[q * NC], &s_nlp[q * NC]);
    } else {
      #pragma unroll
      for (int c = 0; c < NC; c++) s_nlp[q * NC + c] = 0.f;
    }
  }
  for (int c = tid; c < NQP; c += 256) {
    float x = 0.f, y = 0.f, z = 0.f;
    if (c < NQ) { x = PB[c * 7 + 0]; y = PB[c * 7 + 1]; z = PB[c * 7 + 2]; }
    s_pb[c * 3 + 0] = x; s_pb[c * 3 + 1] = y; s_pb[c * 3 + 2] = z;
  }
  __syncthreads();

  float cpx[KS], cpy[KS], cpz[KS];
  #pragma unroll
  for (int k = 0; k < KS; k++) {
    int c = k * 64 + lane;
    cpx[k] = s_pb[c * 3 + 0]; cpy[k] = s_pb[c * 3 + 1]; cpz[k] = s_pb[c * 3 + 2];
  }

  for (int rl = w; rl < 25; rl += 4) {
    int r = rb * 25 + rl;                // 0-based row
    int lab = GL[r];
    float gx = GB[r * 7 + 0], gy = GB[r * 7 + 1], gz = GB[r * 7 + 2];
    float lb = INFF; int bk = 0;
    #pragma unroll
    for (int k = 0; k < KS; k++) {
      int c = k * 64 + lane;
      float nlp = s_nlp[c * NC + lab];
      float d0 = cpx[k] - gx, d1 = cpy[k] - gy, d2 = cpz[k] - gz;
      float bs = fabsf(d0) + fabsf(d1); bs += fabsf(d2);
      float cost = nlp + bs;
      if (c >= NQ) cost = INFF;
      bool bt = cost < lb;
      bk = bt ? k : bk;
      lb = fminf(lb, cost);
    }
    float m1 = wave_min_b(lb);
    unsigned long long msk = __ballot(lb == m1);
    int src = (int)__builtin_ctzll(msk);
    int cstar = __builtin_amdgcn_readlane((bk << 6) | lane, src);  // 0-based col
    if (lane == 0) { wsm[b * NG + r] = m1; wsj[b * NG + r] = cstar; }
  }
}

// ---------- K2: solver, one wave per batch ----------
__global__ __launch_bounds__(64) void solve_kernel(
    const float* __restrict__ logits, const float* __restrict__ pboxes,
    const int* __restrict__ glabels, const float* __restrict__ gboxes,
    const float* __restrict__ wsm, const int* __restrict__ wsj,
    float* __restrict__ out, float inv_B)
{
  const int b = blockIdx.x, lane = threadIdx.x;

  __shared__ float s_nlp[NQP * NC];
  __shared__ float s_u[NG + 1];
  __shared__ int   s_glab[NG];
  __shared__ int   s_claim[NQ];

  const float* L  = logits + (size_t)b * NQ * NC;
  const float* PB = pboxes + (size_t)b * NQ * 7;
  const float* GB = gboxes + (size_t)b * NG * 7;
  const int*   GL = glabels + (size_t)b * NG;

  // ---- staging ----
  for (int q = lane; q < NQP; q += 64) {
    if (q < NQ) {
      nlp7(&L[q * NC], &s_nlp[q * NC]);
    } else {
      #pragma unroll
      for (int c = 0; c < NC; c++) s_nlp[q * NC + c] = 0.f;
    }
  }
  // rows distributed: lane owns rows lane and lane+64 (0-based)
  const int r1 = lane + 64;
  int   rlab0 = GL[lane];
  float rgx0 = GB[lane * 7 + 0], rgy0 = GB[lane * 7 + 1], rgz0 = GB[lane * 7 + 2];
  int   rlab1 = 0; float rgx1 = 0.f, rgy1 = 0.f, rgz1 = 0.f;
  if (r1 < NG) { rlab1 = GL[r1]; rgx1 = GB[r1*7+0]; rgy1 = GB[r1*7+1]; rgz1 = GB[r1*7+2]; }
  s_glab[lane] = rlab0;
  if (r1 < NG) s_glab[r1] = rlab1;
  s_u[lane + 1] = wsm[b * NG + lane];
  if (r1 < NG) s_u[r1 + 1] = wsm[b * NG + r1];
  if (lane == 0) s_u[0] = 0.f;
  int j10 = wsj[b * NG + lane];
  int j11 = (r1 < NG) ? wsj[b * NG + r1] : 0;

  #pragma unroll
  for (int k = 0; k < KS; k++) { int c = k * 64 + lane; if (c < NQ) s_claim[c] = 0x7fffffff; }

  float cpx[KS], cpy[KS], cpz[KS];
  #pragma unroll
  for (int k = 0; k < KS; k++) {
    int c = k * 64 + lane;
    if (c < NQ) { cpx[k] = PB[c*7+0]; cpy[k] = PB[c*7+1]; cpz[k] = PB[c*7+2]; }
    else        { cpx[k] = 0.f; cpy[k] = 0.f; cpz[k] = 0.f; }
  }
  __syncthreads();

  // ---- greedy claims: winner of column = lowest row trying it ----
  atomicMin(&s_claim[j10], lane + 1);          // rows stored 1-based
  if (r1 < NG) atomicMin(&s_claim[j11], r1 + 1);
  __syncthreads();

  int p[KS];
  #pragma unroll
  for (int k = 0; k < KS; k++) {
    int c = k * 64 + lane;
    int wv = (c < NQ) ? s_claim[c] : 0x7fffffff;
    p[k] = (wv == 0x7fffffff) ? 0 : wv;
  }
  bool lose0 = (s_claim[j10] != lane + 1);
  bool lose1 = (r1 < NG) && (s_claim[j11] != r1 + 1);
  unsigned long long fm0 = __ballot(lose0);
  unsigned long long fm1 = __ballot(lose1);

  // ---- JV augmentation for free rows ----
  float v[KS], vmask[KS], ds[KS], dfrz[KS];
  int way[KS];
  #pragma unroll
  for (int k = 0; k < KS; k++) v[k] = 0.f;

  for (int half = 0; half < 2; half++) {
    unsigned long long fm = half ? fm1 : fm0;
    while (fm) {
      int bit = (int)__builtin_ctzll(fm);
      fm &= fm - 1;
      int rfree = bit + (half ? 65 : 1);       // 1-based row
      // init
      #pragma unroll
      for (int k = 0; k < KS; k++) { ds[k] = INFF; way[k] = 0; vmask[k] = v[k]; }
      if (lane >= NQ - 64 * (KS - 1)) vmask[KS - 1] = -INFF;   // invalid cols
      unsigned usedm = 0;
      int i0 = rfree, j0v = 0, jf = -1;
      float minVal = 0.f;

      for (int it = 0; it < 1024; it++) {
        int ro = i0 - 1, rown = ro & 63, rslot = ro >> 6;
        int   lab = __builtin_amdgcn_readlane(rslot ? rlab1 : rlab0, rown);
        float gx = readlane_f(rslot ? rgx1 : rgx0, rown);
        float gy = readlane_f(rslot ? rgy1 : rgy0, rown);
        float gz = readlane_f(rslot ? rgz1 : rgz0, rown);
        float u_i0 = s_u[i0];
        float hs = minVal - u_i0;

        float lb = INFF; int bk = 0;
        #pragma unroll
        for (int k = 0; k < KS; k++) {
          int c = k * 64 + lane;
          float nlp = s_nlp[c * NC + lab];
          float d0 = cpx[k] - gx, d1 = cpy[k] - gy, d2 = cpz[k] - gz;
          float bs = fabsf(d0) + fabsf(d1); bs += fabsf(d2);
          float cost = nlp + bs;
          float rr = (cost + hs) - vmask[k];
          bool imp = rr < ds[k];
          way[k] = imp ? j0v : way[k];
          ds[k] = fminf(ds[k], rr);
          bool bt = ds[k] < lb;
          bk = bt ? k : bk;
          lb = fminf(lb, ds[k]);
        }
        float mn = wave_min_b(lb);
        unsigned long long msk = __ballot(lb == mn);
        int src = (int)__builtin_ctzll(msk);
        int cstar = __builtin_amdgcn_readlane((bk << 6) | lane, src);  // 0-based
        minVal = mn;

        int cown = cstar & 63, cslot = cstar >> 6;
        int pc = 0;
        #pragma unroll
        for (int k = 0; k < KS; k++) if (k == cslot) pc = p[k];
        int pv = __builtin_amdgcn_readlane(pc, cown);
        if (pv == 0) { jf = cstar; break; }
        #pragma unroll
        for (int k = 0; k < KS; k++)
          if (k == cslot && lane == cown) {
            vmask[k] = -INFF; ds[k] = INFF; dfrz[k] = minVal; usedm |= (1u << k);
          }
        i0 = pv; j0v = cstar + 1;                // way stores 1-based prev col
      }

      if (jf >= 0) {
        // deferred potential updates (before augmentation; p[] still pre-augment)
        if (lane == 0) s_u[rfree] += minVal;
        #pragma unroll
        for (int k = 0; k < KS; k++)
          if (usedm & (1u << k)) {
            float a = minVal - dfrz[k];
            v[k] -= a;
            s_u[p[k]] += a;                      // distinct rows -> race-free
          }
        __syncthreads();
        // augment along way
        int jcur = jf;
        for (int it2 = 0; it2 < 1024; it2++) {
          int co = jcur & 63, cs = jcur >> 6;
          int wc = 0;
          #pragma unroll
          for (int k = 0; k < KS; k++) if (k == cs) wc = way[k];
          int wprev = __builtin_amdgcn_readlane(wc, co);
          int pnew;
          if (wprev == 0) pnew = rfree;
          else {
            int c2 = wprev - 1, co2 = c2 & 63, cs2 = c2 >> 6;
            int pc2 = 0;
            #pragma unroll
            for (int k = 0; k < KS; k++) if (k == cs2) pc2 = p[k];
            pnew = __builtin_amdgcn_readlane(pc2, co2);
          }
          #pragma unroll
          for (int k = 0; k < KS; k++) if (k == cs && lane == co) p[k] = pnew;
          if (wprev == 0) break;
          jcur = wprev - 1;
        }
      }
      __syncthreads();
    }
  }

  // ---- matched loss ----
  float ce = 0.f, l1 = 0.f;
  #pragma unroll
  for (int k = 0; k < KS; k++) {
    int c = k * 64 + lane;
    int pr = p[k];
    if (c < NQ && pr > 0) {
      int g = pr - 1;
      ce += s_nlp[c * NC + s_glab[g]];
      float s = 0.f;
      #pragma unroll
      for (int d7 = 0; d7 < 7; d7++) s += fabsf(PB[c * 7 + d7] - GB[g * 7 + d7]);
      l1 += s;
    }
  }
  float tot = ce * (1.f / NG) + l1 * (1.f / (NG * 7.f));
  tot = wave_sum_b(tot);
  if (lane == 0) atomicAdd(out, tot * inv_B);
}

extern "C" void kernel_launch(void* const* d_in, const int* in_sizes, int n_in,
                              void* d_out, int out_size, void* d_ws, size_t ws_size,
                              hipStream_t stream) {
  const float* logits  = (const float*)d_in[0];
  const float* pboxes  = (const float*)d_in[1];
  const int*   glabels = (const int*)d_in[2];
  const float* gboxes  = (const float*)d_in[3];
  float* out = (float*)d_out;
  const int B = in_sizes[0] / (NQ * NC);     // 128

  float* wsm = (float*)d_ws;                 // B*100 row minima
  int*   wsj = (int*)d_ws + (size_t)B * NG;  // B*100 argmin cols (102,400 B total)

  hipMemsetAsync(out, 0, sizeof(float), stream);
  rowmin_kernel<<<dim3(B * 4), dim3(256), 0, stream>>>(
      logits, pboxes, glabels, gboxes, wsm, wsj);
  solve_kernel<<<dim3(B), dim3(64), 0, stream>>>(
      logits, pboxes, glabels, gboxes, wsm, wsj, out, 1.0f / (float)B);
}

// Round 3
// 149.739 us; speedup vs baseline: 2.9627x; 1.0057x over previous
//
#include <hip/hip_runtime.h>
#include <math.h>

// HungarianLoss, fused single kernel. One block (256 threads = 4 waves) per
// batch element:
//   Phase A (4 waves): float4-vectorized staging of logits/pboxes/gboxes/labels
//                      into LDS (one latency exposure, ~50KB per block).
//   Phase B (4 waves): -log_softmax computed in place in LDS.
//   Phase C (4 waves): LAPJV row reduction - per-row min/argmin (25 rows/wave),
//                      greedy column claims via LDS atomicMin.
//   Phase D (wave 0):  JV shortest-augmenting-path for the ~6 unclaimed rows,
//                      deferred dual updates, register-resident v/ds/way/p.
//   Phase E (wave 0):  matched CE + L1 loss from LDS, DPP reduce, atomicAdd.

#define NQ  900    // queries (columns)
#define NQP 960    // padded to 15*64
#define NG  100    // gt boxes (rows)
#define NC  7
#define KS  15     // column slots per lane (wave-wide scan covers 960)
#define INFF __builtin_inff()

__device__ __forceinline__ float readlane_f(float x, int l) {
  return __int_as_float(__builtin_amdgcn_readlane(__float_as_int(x), l));
}

template<int CTRL>
__device__ __forceinline__ float dpp_min_step(float x) {
  int y = __builtin_amdgcn_update_dpp(__float_as_int(x), __float_as_int(x),
                                      CTRL, 0xf, 0xf, false);
  return fminf(x, __int_as_float(y));
}
__device__ __forceinline__ float wave_min_b(float x) {
  x = dpp_min_step<0x111>(x);  // row_shr:1
  x = dpp_min_step<0x112>(x);  // row_shr:2
  x = dpp_min_step<0x114>(x);  // row_shr:4
  x = dpp_min_step<0x118>(x);  // row_shr:8
  x = dpp_min_step<0x142>(x);  // row_bcast:15
  x = dpp_min_step<0x143>(x);  // row_bcast:31
  return __int_as_float(__builtin_amdgcn_readlane(__float_as_int(x), 63));
}

template<int CTRL>
__device__ __forceinline__ float dpp_add_step(float x) {
  int y = __builtin_amdgcn_update_dpp(0, __float_as_int(x),
                                      CTRL, 0xf, 0xf, true);
  return x + __int_as_float(y);
}
__device__ __forceinline__ float wave_sum_b(float x) {
  x = dpp_add_step<0x111>(x);
  x = dpp_add_step<0x112>(x);
  x = dpp_add_step<0x114>(x);
  x = dpp_add_step<0x118>(x);
  x = dpp_add_step<0x142>(x);
  x = dpp_add_step<0x143>(x);
  return __int_as_float(__builtin_amdgcn_readlane(__float_as_int(x), 63));
}

__global__ __launch_bounds__(256) void hungarian_fused_kernel(
    const float* __restrict__ logits, const float* __restrict__ pboxes,
    const int* __restrict__ glabels, const float* __restrict__ gboxes,
    float* __restrict__ out, float inv_B)
{
  const int b = blockIdx.x, tid = threadIdx.x;
  const int lane = tid & 63, w = tid >> 6;

  __shared__ __align__(16) float s_nlp[NQP * NC];  // raw logits -> nlp in place
  __shared__ __align__(16) float s_pb[NQP * NC];   // raw pred boxes (7 dims)
  __shared__ __align__(16) float s_gb[NG * NC];    // gt boxes (7 dims)
  __shared__ int   s_glab[NG];
  __shared__ float s_u[NG + 1];                    // row potentials (1-based)
  __shared__ int   s_j1[NG];                       // per-row argmin column
  __shared__ int   s_claim[NQ];

  // ---- Phase A: staging ----
  {
    const float4* gl4 = (const float4*)(logits + (size_t)b * NQ * NC);
    const float4* gp4 = (const float4*)(pboxes + (size_t)b * NQ * NC);
    float4* sn4 = (float4*)s_nlp;
    float4* sp4 = (float4*)s_pb;
    float4 ta[7], tb[7];
    #pragma unroll
    for (int t = 0; t < 7; t++) {
      int i = tid + (t << 8);
      if (i < (NQ * NC) / 4) { ta[t] = gl4[i]; tb[t] = gp4[i]; }
    }
    #pragma unroll
    for (int t = 0; t < 7; t++) {
      int i = tid + (t << 8);
      if (i < (NQ * NC) / 4) { sn4[i] = ta[t]; sp4[i] = tb[t]; }
    }
    if (tid < (NG * NC) / 4)
      ((float4*)s_gb)[tid] = ((const float4*)(gboxes + (size_t)b * NG * NC))[tid];
    if (tid < NG) s_glab[tid] = glabels[(size_t)b * NG + tid];
    // zero the padded tail (queries 900..959) so no NaN flows anywhere
    for (int i = tid; i < (NQP - NQ) * NC; i += 256) {
      s_nlp[NQ * NC + i] = 0.f; s_pb[NQ * NC + i] = 0.f;
    }
    for (int c = tid; c < NQ; c += 256) s_claim[c] = 0x7fffffff;
    if (tid == 0) s_u[0] = 0.f;
  }
  __syncthreads();

  // ---- Phase B: -log_softmax in place ----
  for (int q = tid; q < NQP; q += 256) {
    float x[NC];
    #pragma unroll
    for (int c = 0; c < NC; c++) x[c] = s_nlp[q * NC + c];
    float mx = x[0];
    #pragma unroll
    for (int c = 1; c < NC; c++) mx = fmaxf(mx, x[c]);
    float t[NC]; float se = 0.f;
    #pragma unroll
    for (int c = 0; c < NC; c++) { t[c] = x[c] - mx; se += __expf(t[c]); }
    float lg = __logf(se);
    #pragma unroll
    for (int c = 0; c < NC; c++) s_nlp[q * NC + c] = lg - t[c];
  }
  __syncthreads();

  // per-lane column xyz (shared by Phase C scan and Phase D Dijkstra)
  float cpx[KS], cpy[KS], cpz[KS];
  #pragma unroll
  for (int k = 0; k < KS; k++) {
    int c = (k << 6) + lane;
    cpx[k] = s_pb[c * NC + 0]; cpy[k] = s_pb[c * NC + 1]; cpz[k] = s_pb[c * NC + 2];
  }

  // ---- Phase C: row reduction (25 rows per wave) + greedy claims ----
  for (int rl = 0; rl < 25; rl++) {
    int r = w * 25 + rl;
    int lab = s_glab[r];
    float gx = s_gb[r * NC + 0], gy = s_gb[r * NC + 1], gz = s_gb[r * NC + 2];
    float lb = INFF; int bk = 0;
    #pragma unroll
    for (int k = 0; k < KS; k++) {
      int c = (k << 6) + lane;
      float nlp = s_nlp[c * NC + lab];
      float bs = fabsf(cpx[k] - gx) + fabsf(cpy[k] - gy); bs += fabsf(cpz[k] - gz);
      float cost = nlp + bs;
      if (c >= NQ) cost = INFF;
      bool bt = cost < lb;
      bk = bt ? k : bk;
      lb = fminf(lb, cost);
    }
    float m1 = wave_min_b(lb);
    unsigned long long msk = __ballot(lb == m1);
    int src = (int)__builtin_ctzll(msk);
    int cstar = __builtin_amdgcn_readlane((bk << 6) | lane, src);  // 0-based col
    if (lane == 0) {
      s_u[r + 1] = m1;
      s_j1[r] = cstar;
      atomicMin(&s_claim[cstar], r + 1);   // winner = lowest row (1-based)
    }
  }
  __syncthreads();
  if (w != 0) return;   // waves 1-3 done; no barriers beyond this point

  // ---- Phase D: JV augmentation (wave 0 only) ----
  int j10 = s_j1[lane];
  int j11 = (lane < NG - 64) ? s_j1[64 + lane] : 0;
  bool lose0 = (s_claim[j10] != lane + 1);
  bool lose1 = (lane < NG - 64) && (s_claim[j11] != lane + 65);
  unsigned long long fm0 = __ballot(lose0);
  unsigned long long fm1 = __ballot(lose1);

  int p[KS];
  #pragma unroll
  for (int k = 0; k < KS; k++) {
    int c = (k << 6) + lane;
    int wv = (c < NQ) ? s_claim[c] : 0x7fffffff;
    p[k] = (wv == 0x7fffffff) ? 0 : wv;
  }

  volatile float* vu = s_u;
  float v[KS], vmask[KS], ds[KS], dfrz[KS];
  int way[KS];
  #pragma unroll
  for (int k = 0; k < KS; k++) v[k] = 0.f;

  for (int half = 0; half < 2; half++) {
    unsigned long long fm = half ? fm1 : fm0;
    while (fm) {
      int bit = (int)__builtin_ctzll(fm);
      fm &= fm - 1;
      int rfree = bit + (half ? 65 : 1);       // 1-based row
      #pragma unroll
      for (int k = 0; k < KS; k++) { ds[k] = INFF; way[k] = 0; vmask[k] = v[k]; }
      if (lane >= NQ - 64 * (KS - 1)) vmask[KS - 1] = -INFF;   // invalid cols
      unsigned usedm = 0;
      int i0 = rfree, j0v = 0, jf = -1;
      float minVal = 0.f;

      for (int it = 0; it < 1024; it++) {
        int ro = i0 - 1;
        int   lab = s_glab[ro];
        float gx = s_gb[ro * NC + 0], gy = s_gb[ro * NC + 1], gz = s_gb[ro * NC + 2];
        float u_i0 = vu[i0];
        float hs = minVal - u_i0;

        float lb = INFF; int bk = 0;
        #pragma unroll
        for (int k = 0; k < KS; k++) {
          int c = (k << 6) + lane;
          float nlp = s_nlp[c * NC + lab];
          float bs = fabsf(cpx[k] - gx) + fabsf(cpy[k] - gy); bs += fabsf(cpz[k] - gz);
          float cost = nlp + bs;
          float rr = (cost + hs) - vmask[k];
          bool imp = rr < ds[k];
          way[k] = imp ? j0v : way[k];
          ds[k] = fminf(ds[k], rr);
          bool bt = ds[k] < lb;
          bk = bt ? k : bk;
          lb = fminf(lb, ds[k]);
        }
        float mn = wave_min_b(lb);
        unsigned long long msk = __ballot(lb == mn);
        int src = (int)__builtin_ctzll(msk);
        int cstar = __builtin_amdgcn_readlane((bk << 6) | lane, src);  // 0-based
        minVal = mn;

        int cown = cstar & 63, cslot = cstar >> 6;
        int pc = 0;
        #pragma unroll
        for (int k = 0; k < KS; k++) if (k == cslot) pc = p[k];
        int pv = __builtin_amdgcn_readlane(pc, cown);
        if (pv == 0) { jf = cstar; break; }
        #pragma unroll
        for (int k = 0; k < KS; k++)
          if (k == cslot && lane == cown) {
            vmask[k] = -INFF; ds[k] = INFF; dfrz[k] = minVal; usedm |= (1u << k);
          }
        i0 = pv; j0v = cstar + 1;                // way stores 1-based prev col
      }

      if (jf >= 0) {
        // deferred dual updates (p[] still pre-augmentation)
        if (lane == 0) vu[rfree] += minVal;
        #pragma unroll
        for (int k = 0; k < KS; k++)
          if (usedm & (1u << k)) {
            float a = minVal - dfrz[k];
            v[k] -= a;
            vu[p[k]] += a;                       // distinct rows -> race-free
          }
        __threadfence_block();
        // augment along way
        int jcur = jf;
        for (int it2 = 0; it2 < 1024; it2++) {
          int co = jcur & 63, cs = jcur >> 6;
          int wc = 0;
          #pragma unroll
          for (int k = 0; k < KS; k++) if (k == cs) wc = way[k];
          int wprev = __builtin_amdgcn_readlane(wc, co);
          int pnew;
          if (wprev == 0) pnew = rfree;
          else {
            int c2 = wprev - 1, co2 = c2 & 63, cs2 = c2 >> 6;
            int pc2 = 0;
            #pragma unroll
            for (int k = 0; k < KS; k++) if (k == cs2) pc2 = p[k];
            pnew = __builtin_amdgcn_readlane(pc2, co2);
          }
          #pragma unroll
          for (int k = 0; k < KS; k++) if (k == cs && lane == co) p[k] = pnew;
          if (wprev == 0) break;
          jcur = wprev - 1;
        }
      }
      __threadfence_block();
    }
  }

  // ---- Phase E: matched loss (wave 0, all data in LDS) ----
  float ce = 0.f, l1 = 0.f;
  #pragma unroll
  for (int k = 0; k < KS; k++) {
    int c = (k << 6) + lane;
    int pr = p[k];
    if (c < NQ && pr > 0) {
      int g = pr - 1;
      ce += s_nlp[c * NC + s_glab[g]];
      float s = 0.f;
      #pragma unroll
      for (int d7 = 0; d7 < 7; d7++) s += fabsf(s_pb[c * NC + d7] - s_gb[g * NC + d7]);
      l1 += s;
    }
  }
  float tot = ce * (1.f / NG) + l1 * (1.f / (NG * 7.f));
  tot = wave_sum_b(tot);
  if (lane == 0) atomicAdd(out, tot * inv_B);
}

extern "C" void kernel_launch(void* const* d_in, const int* in_sizes, int n_in,
                              void* d_out, int out_size, void* d_ws, size_t ws_size,
                              hipStream_t stream) {
  const float* logits  = (const float*)d_in[0];
  const float* pboxes  = (const float*)d_in[1];
  const int*   glabels = (const int*)d_in[2];
  const float* gboxes  = (const float*)d_in[3];
  float* out = (float*)d_out;
  const int B = in_sizes[0] / (NQ * NC);     // 128

  hipMemsetAsync(out, 0, sizeof(float), stream);
  hungarian_fused_kernel<<<dim3(B), dim3(256), 0, stream>>>(
      logits, pboxes, glabels, gboxes, out, 1.0f / (float)B);
}